// Round 1
// baseline (201.552 us; speedup 1.0000x reference)
//
#include <hip/hip_runtime.h>
#include <math.h>

// Problem constants (fixed by setup_inputs): pred (8,4,256,256) f32,
// target (8,256,256) i32, boundary_weight (8,1,256,256) f32 -> scalar f32.
constexpr int B = 8;
constexpr int C = 4;
constexpr int H = 256;
constexpr int W = 256;
constexpr int NC = C - 1;          // classes 1..3
constexpr int NIMG = B * NC;       // 24 (b, c) images
constexpr float EDT_INF = 1e10f;   // matches reference INF
constexpr float LOSS_SCALE = 1.0f / (float)(NC * B * H * W); // mean over (B,H,W), /3

// ---------------------------------------------------------------------------
// Kernel 1: per-row two-scan 1D column distances -> squared, transposed store.
// grid = NIMG*4 blocks, 64 threads; thread handles one row of one (b,c) image.
// g layout: [img][j][i]  (transposed) so writes here and column loads in
// kernel 2 are both coalesced (threads vary i contiguously).
// ---------------------------------------------------------------------------
__global__ void rowscan_kernel(const int* __restrict__ target,
                               float* __restrict__ g_m,
                               float* __restrict__ g_nm,
                               int* __restrict__ counts) {
    const int img = blockIdx.x >> 2;            // 0..23
    const int rb  = blockIdx.x & 3;             // row block 0..3
    const int i   = rb * 64 + threadIdx.x;      // row 0..255
    const int b   = img / NC;
    const int c   = img % NC + 1;

    const int* trow = target + (b * H + i) * W;
    float* gm  = g_m  + (size_t)img * H * W;    // index [j*H + i]
    float* gnm = g_nm + (size_t)img * H * W;

    // forward scan: distance to nearest site at <= j
    int last_m = -(1 << 20);
    int last_nm = -(1 << 20);
    int cnt = 0;
    for (int j = 0; j < W; ++j) {
        const bool m = (trow[j] == c);
        cnt += m ? 1 : 0;
        if (m) last_m = j; else last_nm = j;
        gm[j * H + i]  = (float)(j - last_m);
        gnm[j * H + i] = (float)(j - last_nm);
    }
    // backward scan: min with distance to nearest site at >= j, then square
    int next_m = (1 << 20);
    int next_nm = (1 << 20);
    for (int j = W - 1; j >= 0; --j) {
        const bool m = (trow[j] == c);
        if (m) next_m = j; else next_nm = j;
        float fm  = fminf(gm[j * H + i],  (float)(next_m - j));
        float fnm = fminf(gnm[j * H + i], (float)(next_nm - j));
        gm[j * H + i]  = (fm  <= 255.0f) ? fm * fm   : EDT_INF;
        gnm[j * H + i] = (fnm <= 255.0f) ? fnm * fnm : EDT_INF;
    }
    // mask count (degenerate check): wave-64 reduce, one atomic per block
    for (int off = 32; off > 0; off >>= 1) cnt += __shfl_down(cnt, off, 64);
    if (threadIdx.x == 0) atomicAdd(&counts[img], cnt);
}

// ---------------------------------------------------------------------------
// Kernel 2: row-direction min-plus envelope + fused loss.
// block = (img, column j), 256 threads = output rows i.
// ---------------------------------------------------------------------------
__global__ void envelope_loss_kernel(const float* __restrict__ pred,
                                     const int* __restrict__ target,
                                     const float* __restrict__ wmap,
                                     const float* __restrict__ g_m,
                                     const float* __restrict__ g_nm,
                                     const int* __restrict__ counts,
                                     float* __restrict__ out) {
    const int blk = blockIdx.x;
    const int img = blk / W;
    const int j   = blk % W;
    const int b   = img / NC;
    const int c   = img % NC + 1;
    const int i   = threadIdx.x;

    __shared__ float sm[H];
    __shared__ float snm[H];
    sm[i]  = g_m [((size_t)img * W + j) * H + i];
    snm[i] = g_nm[((size_t)img * W + j) * H + i];
    __syncthreads();

    // min-plus lower envelope over rows (LDS broadcast reads: conflict-free)
    const float fi = (float)i;
    float d2m = EDT_INF, d2nm = EDT_INF;
#pragma unroll 8
    for (int ip = 0; ip < H; ++ip) {
        const float d  = fi - (float)ip;
        const float dd = d * d;
        d2m  = fminf(d2m,  sm[ip]  + dd);
        d2nm = fminf(d2nm, snm[ip] + dd);
    }

    const int n = counts[img];
    const float dist = (n == 0 || n == H * W) ? 0.0f
                                              : (sqrtf(d2m) + sqrtf(d2nm));

    // fused loss: |softmax_c - t_c| * w * dist
    const int pix = (b * H + i) * W + j;
    const float tc = (target[pix] == c) ? 1.0f : 0.0f;
    const float wv = wmap[pix];
    const float* pp = pred + ((size_t)b * C * H + i) * W + j;
    const float p0 = pp[0];
    const float p1 = pp[(size_t)H * W];
    const float p2 = pp[2 * (size_t)H * W];
    const float p3 = pp[3 * (size_t)H * W];
    const float mx = fmaxf(fmaxf(p0, p1), fmaxf(p2, p3));
    const float e0 = __expf(p0 - mx);
    const float e1 = __expf(p1 - mx);
    const float e2 = __expf(p2 - mx);
    const float e3 = __expf(p3 - mx);
    const float inv = 1.0f / (e0 + e1 + e2 + e3);
    const float pc = ((c == 1) ? e1 : (c == 2) ? e2 : e3) * inv;
    float v = fabsf(pc - tc) * wv * dist;

    // block reduction: wave shuffle + LDS across 4 waves
    for (int off = 32; off > 0; off >>= 1) v += __shfl_down(v, off, 64);
    __shared__ float swave[4];
    const int lane = i & 63, wid = i >> 6;
    if (lane == 0) swave[wid] = v;
    __syncthreads();
    if (i == 0) {
        const float s = swave[0] + swave[1] + swave[2] + swave[3];
        atomicAdd(out, s * LOSS_SCALE);
    }
}

// ---------------------------------------------------------------------------
extern "C" void kernel_launch(void* const* d_in, const int* in_sizes, int n_in,
                              void* d_out, int out_size, void* d_ws, size_t ws_size,
                              hipStream_t stream) {
    const float* pred   = (const float*)d_in[0];
    const int*   target = (const int*)d_in[1];
    const float* wmap   = (const float*)d_in[2];
    float* out = (float*)d_out;

    float* g_m  = (float*)d_ws;
    float* g_nm = g_m + (size_t)NIMG * H * W;
    int*   counts = (int*)(g_nm + (size_t)NIMG * H * W);

    hipMemsetAsync(d_out, 0, sizeof(float), stream);
    hipMemsetAsync(counts, 0, NIMG * sizeof(int), stream);

    rowscan_kernel<<<NIMG * 4, 64, 0, stream>>>(target, g_m, g_nm, counts);
    envelope_loss_kernel<<<NIMG * W, 256, 0, stream>>>(pred, target, wmap,
                                                       g_m, g_nm, counts, out);
}

// Round 2
// 127.106 us; speedup vs baseline: 1.5857x; 1.5857x over previous
//
#include <hip/hip_runtime.h>
#include <math.h>

// pred (8,4,256,256) f32, target (8,256,256) i32, w (8,1,256,256) f32 -> scalar.
constexpr int B = 8;
constexpr int C = 4;
constexpr int H = 256;
constexpr int W = 256;
constexpr int NC = C - 1;          // classes 1..3
constexpr int NIMG = B * NC;       // 24
constexpr float EDT_INF = 1e10f;   // matches reference INF
constexpr float LOSS_SCALE = 1.0f / (float)(NC * B * H * W);
constexpr int BIGI = 1 << 20;

// ---------------------------------------------------------------------------
// K1: per-(img,row) 1D nearest-site column distance via ballot bit-scans.
// block = (img, i), 256 threads = j. Output g[img][j][i] (transposed so K2's
// column loads are coalesced); squared distance or EDT_INF for empty rows.
// ---------------------------------------------------------------------------
__global__ __launch_bounds__(256) void rowscan_kernel(
        const int* __restrict__ target,
        float* __restrict__ g_m, float* __restrict__ g_nm) {
    const int img = blockIdx.x >> 8;
    const int i   = blockIdx.x & (H - 1);
    const int b   = img / NC;
    const int c   = img - b * NC + 1;
    const int j   = threadIdx.x;
    const int lane  = j & 63;
    const int wid   = j >> 6;
    const int wbase = wid << 6;

    const int tv = target[(b * H + i) * W + j];
    const bool m = (tv == c);
    const unsigned long long bm = __ballot(m);
    const unsigned long long bn = ~bm;   // block fully active: complement valid

    __shared__ int wlast[2][4];   // highest site j in wave (or -BIGI)
    __shared__ int wfirst[2][4];  // lowest  site j in wave (or +BIGI)
    if (lane == 0) {
        wlast [0][wid] = bm ? (wbase + 63 - __clzll(bm))                    : -BIGI;
        wfirst[0][wid] = bm ? (wbase + (int)__ffsll((unsigned long long)bm) - 1) : BIGI;
        wlast [1][wid] = bn ? (wbase + 63 - __clzll(bn))                    : -BIGI;
        wfirst[1][wid] = bn ? (wbase + (int)__ffsll((unsigned long long)bn) - 1) : BIGI;
    }
    __syncthreads();

    const size_t gidx = ((size_t)img * W + j) * H + i;

    #pragma unroll
    for (int sel = 0; sel < 2; ++sel) {
        const unsigned long long bb = sel ? bn : bm;
        // nearest site at index <= j
        const unsigned long long below = bb << (63 - lane);
        int lastw = -BIGI;
        #pragma unroll
        for (int w = 0; w < 3; ++w) if (w < wid) lastw = max(lastw, wlast[sel][w]);
        const int last = below ? (j - __clzll(below)) : lastw;
        // nearest site at index >= j
        const unsigned long long above = bb >> lane;
        int firstw = BIGI;
        #pragma unroll
        for (int w = 1; w < 4; ++w) if (w > wid) firstw = min(firstw, wfirst[sel][w]);
        const int nxt = above ? (j + (int)__ffsll((unsigned long long)above) - 1) : firstw;

        const int fm = min(j - last, nxt - j);
        const float g = (fm <= 255) ? (float)(fm * fm) : EDT_INF;
        if (sel == 0) g_m[gidx] = g; else g_nm[gidx] = g;
    }
}

// ---------------------------------------------------------------------------
// K2: row-direction min-plus envelope + fused loss.
// block = (img, j), 256 threads = i. Per pixel only the OPPOSITE-set distance
// is needed (the own-set term is exactly 0), halving envelope work.
// Linearized: d2(i) = i^2 + min_ip (h[ip] - 2*i*ip), h = g + ip^2 (exact fp32
// for all finite candidates). Degenerate masks show up as d2 ~ 1e10 -> 0.
// ---------------------------------------------------------------------------
__global__ __launch_bounds__(256) void envelope_loss_kernel(
        const float* __restrict__ pred,
        const int* __restrict__ target,
        const float* __restrict__ wmap,
        const float* __restrict__ g_m,
        const float* __restrict__ g_nm,
        float* __restrict__ partials) {
    const int img = blockIdx.x >> 8;
    const int j   = blockIdx.x & (W - 1);
    const int b   = img / NC;
    const int c   = img - b * NC + 1;
    const int i   = threadIdx.x;
    const float fi = (float)i;

    __shared__ __align__(16) float sm[H];
    __shared__ __align__(16) float snm[H];

    const size_t gbase = ((size_t)img * W + j) * H;
    sm[i]  = g_m [gbase + i] + fi * fi;
    snm[i] = g_nm[gbase + i] + fi * fi;

    const int pix = (b * H + i) * W + j;
    const int tv  = target[pix];
    const bool in_c = (tv == c);
    __syncthreads();

    // pixel in class c -> its m-distance is 0, need edt(~m); else edt(m).
    const float* hp = in_c ? snm : sm;
    const float4* h4 = (const float4*)hp;
    const float m2i = -2.0f * fi;

    float b0 = EDT_INF, b1 = EDT_INF, b2 = EDT_INF, b3 = EDT_INF;
    float f0 = 0.f, f1 = 1.f, f2 = 2.f, f3 = 3.f;
    #pragma unroll 8
    for (int k = 0; k < H / 4; ++k) {
        const float4 h = h4[k];
        b0 = fminf(b0, fmaf(m2i, f0, h.x));
        b1 = fminf(b1, fmaf(m2i, f1, h.y));
        b2 = fminf(b2, fmaf(m2i, f2, h.z));
        b3 = fminf(b3, fmaf(m2i, f3, h.w));
        f0 += 4.f; f1 += 4.f; f2 += 4.f; f3 += 4.f;
    }
    const float d2 = fminf(fminf(b0, b1), fminf(b2, b3)) + fi * fi;
    const float dist = (d2 < 1e9f) ? sqrtf(d2) : 0.0f;  // 1e10 <=> degenerate

    // fused loss: |softmax_c - t_c| * w * dist
    const float tc = in_c ? 1.0f : 0.0f;
    const float wv = wmap[pix];
    const float* pp = pred + ((size_t)b * C * H + i) * W + j;
    const float p0 = pp[0];
    const float p1 = pp[(size_t)H * W];
    const float p2 = pp[2 * (size_t)H * W];
    const float p3 = pp[3 * (size_t)H * W];
    const float mx = fmaxf(fmaxf(p0, p1), fmaxf(p2, p3));
    const float e0 = __expf(p0 - mx);
    const float e1 = __expf(p1 - mx);
    const float e2 = __expf(p2 - mx);
    const float e3 = __expf(p3 - mx);
    const float inv = 1.0f / (e0 + e1 + e2 + e3);
    const float pc = ((c == 1) ? e1 : (c == 2) ? e2 : e3) * inv;
    float v = fabsf(pc - tc) * wv * dist;

    for (int off = 32; off > 0; off >>= 1) v += __shfl_down(v, off, 64);
    __shared__ float swave[4];
    const int lane = i & 63, wid = i >> 6;
    if (lane == 0) swave[wid] = v;
    __syncthreads();
    if (i == 0) partials[blockIdx.x] = swave[0] + swave[1] + swave[2] + swave[3];
}

// ---------------------------------------------------------------------------
// K3: deterministic final reduction of NIMG*W partials (no global atomics).
// ---------------------------------------------------------------------------
__global__ __launch_bounds__(256) void reduce_kernel(
        const float* __restrict__ partials, float* __restrict__ out) {
    const int t = threadIdx.x;
    float v = 0.0f;
    #pragma unroll
    for (int k = 0; k < NIMG * W / 256; ++k) v += partials[k * 256 + t];
    for (int off = 32; off > 0; off >>= 1) v += __shfl_down(v, off, 64);
    __shared__ float swave[4];
    const int lane = t & 63, wid = t >> 6;
    if (lane == 0) swave[wid] = v;
    __syncthreads();
    if (t == 0) out[0] = (swave[0] + swave[1] + swave[2] + swave[3]) * LOSS_SCALE;
}

// ---------------------------------------------------------------------------
extern "C" void kernel_launch(void* const* d_in, const int* in_sizes, int n_in,
                              void* d_out, int out_size, void* d_ws, size_t ws_size,
                              hipStream_t stream) {
    const float* pred   = (const float*)d_in[0];
    const int*   target = (const int*)d_in[1];
    const float* wmap   = (const float*)d_in[2];
    float* out = (float*)d_out;

    float* g_m      = (float*)d_ws;
    float* g_nm     = g_m  + (size_t)NIMG * H * W;
    float* partials = g_nm + (size_t)NIMG * H * W;

    rowscan_kernel<<<NIMG * H, 256, 0, stream>>>(target, g_m, g_nm);
    envelope_loss_kernel<<<NIMG * W, 256, 0, stream>>>(pred, target, wmap,
                                                       g_m, g_nm, partials);
    reduce_kernel<<<1, 256, 0, stream>>>(partials, out);
}

// Round 3
// 118.221 us; speedup vs baseline: 1.7049x; 1.0752x over previous
//
#include <hip/hip_runtime.h>
#include <math.h>

// pred (8,4,256,256) f32, target (8,256,256) i32, w (8,1,256,256) f32 -> scalar.
constexpr int B = 8;
constexpr int C = 4;
constexpr int H = 256;
constexpr int W = 256;
constexpr int NC = C - 1;          // classes 1..3
constexpr int NIMG = B * NC;       // 24
constexpr float EDT_INF = 1e10f;   // matches reference INF
constexpr float LOSS_SCALE = 1.0f / (float)(NC * B * H * W);
constexpr int BIGI = 1 << 20;
constexpr int TR = 16;             // rows per rowscan tile

// ---------------------------------------------------------------------------
// K1: ballot-based 1D column-distance scan, 16 rows per block, LDS transpose,
// fully-coalesced full-line float4 writes to g[img][j][i].
// grid = NIMG * (H/TR) = 384 blocks, 256 threads (= j).
// ---------------------------------------------------------------------------
__global__ __launch_bounds__(256) void rowscan_kernel(
        const int* __restrict__ target,
        float* __restrict__ g_m, float* __restrict__ g_nm) {
    const int img  = blockIdx.x / (H / TR);
    const int tile = blockIdx.x % (H / TR);
    const int i0   = tile * TR;
    const int b    = img / NC;
    const int c    = img - b * NC + 1;
    const int j    = threadIdx.x;
    const int lane = j & 63, wid = j >> 6, wbase = wid << 6;

    __shared__ unsigned long long smask[2][TR][4];
    __shared__ int swlast[2][TR][4];
    __shared__ int swfirst[2][TR][4];
    __shared__ float tm[TR][W + 1];   // +1 pad: phase-C writes conflict-free
    __shared__ float tn[TR][W + 1];

    // Phase A: per-row ballots + per-wave first/last site indices
    for (int r = 0; r < TR; ++r) {
        const int tv = target[(b * H + i0 + r) * W + j];
        const unsigned long long bm = __ballot(tv == c);
        if (lane == 0) {
            const unsigned long long bn = ~bm;
            smask[0][r][wid] = bm;
            smask[1][r][wid] = bn;
            swlast [0][r][wid] = bm ? (wbase + 63 - __clzll(bm)) : -BIGI;
            swfirst[0][r][wid] = bm ? (wbase + (int)__ffsll(bm) - 1) : BIGI;
            swlast [1][r][wid] = bn ? (wbase + 63 - __clzll(bn)) : -BIGI;
            swfirst[1][r][wid] = bn ? (wbase + (int)__ffsll(bn) - 1) : BIGI;
        }
    }
    __syncthreads();

    // Phase C: nearest-site distances -> squared, into LDS tiles
    for (int r = 0; r < TR; ++r) {
        #pragma unroll
        for (int sel = 0; sel < 2; ++sel) {
            const unsigned long long bb = smask[sel][r][wid];
            const unsigned long long below = bb << (63 - lane);
            int last = -BIGI;
            #pragma unroll
            for (int w = 0; w < 3; ++w) if (w < wid) last = max(last, swlast[sel][r][w]);
            if (below) last = j - __clzll(below);
            const unsigned long long above = bb >> lane;
            int nxt = BIGI;
            #pragma unroll
            for (int w = 1; w < 4; ++w) if (w > wid) nxt = min(nxt, swfirst[sel][r][w]);
            if (above) nxt = j + (int)__ffsll(above) - 1;
            const int fm = min(j - last, nxt - j);
            const float g = (fm <= 255) ? (float)(fm * fm) : EDT_INF;
            if (sel == 0) tm[r][j] = g; else tn[r][j] = g;
        }
    }
    __syncthreads();

    // Phase E: transposed write-out, full-64B-line float4 stores
    const size_t base = (size_t)img * W * H;
    #pragma unroll
    for (int p = 0; p < 4; ++p) {
        const int v    = p * 256 + threadIdx.x;
        const int jj   = v >> 2;
        const int rr   = (v & 3) * 4;
        float4 o;
        o.x = tm[rr][jj]; o.y = tm[rr + 1][jj]; o.z = tm[rr + 2][jj]; o.w = tm[rr + 3][jj];
        *(float4*)(g_m + base + (size_t)jj * H + i0 + rr) = o;
        float4 q;
        q.x = tn[rr][jj]; q.y = tn[rr + 1][jj]; q.z = tn[rr + 2][jj]; q.w = tn[rr + 3][jj];
        *(float4*)(g_nm + base + (size_t)jj * H + i0 + rr) = q;
    }
}

// ---------------------------------------------------------------------------
// K2: row-direction min-plus envelope + fused loss. block = (img, j),
// 256 threads = i. Only the opposite-set distance is nonzero per pixel.
// h-arrays interleaved at float4 granularity so the two divergent ds_read
// addresses land on disjoint 4-bank groups (no LDS conflicts).
// ---------------------------------------------------------------------------
__global__ __launch_bounds__(256) void envelope_loss_kernel(
        const float* __restrict__ pred,
        const int* __restrict__ target,
        const float* __restrict__ wmap,
        const float* __restrict__ g_m,
        const float* __restrict__ g_nm,
        float* __restrict__ partials) {
    const int img = blockIdx.x >> 8;
    const int j   = blockIdx.x & (W - 1);
    const int b   = img / NC;
    const int c   = img - b * NC + 1;
    const int i   = threadIdx.x;
    const float fi  = (float)i;
    const float fi2 = fi * fi;

    __shared__ __align__(16) float s[2 * H];  // [k][sel][4] interleaved

    const size_t gbase = ((size_t)img * W + j) * H;
    s[(i >> 2) * 8 + (i & 3)]     = g_m [gbase + i] + fi2;  // h_m
    s[(i >> 2) * 8 + 4 + (i & 3)] = g_nm[gbase + i] + fi2;  // h_nm

    const int pix = (b * H + i) * W + j;
    const int tv  = target[pix];
    const bool in_c = (tv == c);
    __syncthreads();

    // pixel in class c -> needs edt(~m); else edt(m).
    const float4* h4 = ((const float4*)s) + (in_c ? 1 : 0);
    const float m2i = -2.0f * fi;

    float b0 = EDT_INF, b1 = EDT_INF, b2 = EDT_INF, b3 = EDT_INF;
    float f0 = 0.f, f1 = 1.f, f2 = 2.f, f3 = 3.f;
    #pragma unroll 8
    for (int k = 0; k < H / 4; ++k) {
        const float4 h = h4[2 * k];
        b0 = fminf(b0, fmaf(m2i, f0, h.x));
        b1 = fminf(b1, fmaf(m2i, f1, h.y));
        b2 = fminf(b2, fmaf(m2i, f2, h.z));
        b3 = fminf(b3, fmaf(m2i, f3, h.w));
        f0 += 4.f; f1 += 4.f; f2 += 4.f; f3 += 4.f;
    }
    const float d2 = fminf(fminf(b0, b1), fminf(b2, b3)) + fi2;
    const float dist = (d2 < 1e9f) ? sqrtf(d2) : 0.0f;  // ~1e10 <=> degenerate

    // fused loss: |softmax_c - t_c| * w * dist
    const float tc = in_c ? 1.0f : 0.0f;
    const float wv = wmap[pix];
    const float* pp = pred + ((size_t)b * C * H + i) * W + j;
    const float p0 = pp[0];
    const float p1 = pp[(size_t)H * W];
    const float p2 = pp[2 * (size_t)H * W];
    const float p3 = pp[3 * (size_t)H * W];
    const float mx = fmaxf(fmaxf(p0, p1), fmaxf(p2, p3));
    const float e0 = __expf(p0 - mx);
    const float e1 = __expf(p1 - mx);
    const float e2 = __expf(p2 - mx);
    const float e3 = __expf(p3 - mx);
    const float inv = 1.0f / (e0 + e1 + e2 + e3);
    const float pc = ((c == 1) ? e1 : (c == 2) ? e2 : e3) * inv;
    float v = fabsf(pc - tc) * wv * dist;

    for (int off = 32; off > 0; off >>= 1) v += __shfl_down(v, off, 64);
    __shared__ float swave[4];
    const int lane = i & 63, wid = i >> 6;
    if (lane == 0) swave[wid] = v;
    __syncthreads();
    if (i == 0) partials[blockIdx.x] = swave[0] + swave[1] + swave[2] + swave[3];
}

// ---------------------------------------------------------------------------
// K3: deterministic final reduction of NIMG*W partials.
// ---------------------------------------------------------------------------
__global__ __launch_bounds__(256) void reduce_kernel(
        const float* __restrict__ partials, float* __restrict__ out) {
    const int t = threadIdx.x;
    float v = 0.0f;
    #pragma unroll
    for (int k = 0; k < NIMG * W / 256; ++k) v += partials[k * 256 + t];
    for (int off = 32; off > 0; off >>= 1) v += __shfl_down(v, off, 64);
    __shared__ float swave[4];
    const int lane = t & 63, wid = t >> 6;
    if (lane == 0) swave[wid] = v;
    __syncthreads();
    if (t == 0) out[0] = (swave[0] + swave[1] + swave[2] + swave[3]) * LOSS_SCALE;
}

// ---------------------------------------------------------------------------
extern "C" void kernel_launch(void* const* d_in, const int* in_sizes, int n_in,
                              void* d_out, int out_size, void* d_ws, size_t ws_size,
                              hipStream_t stream) {
    const float* pred   = (const float*)d_in[0];
    const int*   target = (const int*)d_in[1];
    const float* wmap   = (const float*)d_in[2];
    float* out = (float*)d_out;

    float* g_m      = (float*)d_ws;
    float* g_nm     = g_m  + (size_t)NIMG * H * W;
    float* partials = g_nm + (size_t)NIMG * H * W;

    rowscan_kernel<<<NIMG * (H / TR), 256, 0, stream>>>(target, g_m, g_nm);
    envelope_loss_kernel<<<NIMG * W, 256, 0, stream>>>(pred, target, wmap,
                                                       g_m, g_nm, partials);
    reduce_kernel<<<1, 256, 0, stream>>>(partials, out);
}